// Round 1
// 1987.542 us; speedup vs baseline: 1.3430x; 1.3430x over previous
//
#include <hip/hip_runtime.h>
#include <hip/hip_bf16.h>
#include <cstdint>
#include <cstddef>

// Problem constants
#define B_  32
#define T_  128
#define E_  4096
#define H_  32
#define DK_ 128
#define F_  16384
#define M_  4096   // B_*T_

typedef __bf16 bf16x8 __attribute__((ext_vector_type(8)));
typedef float  f32x4  __attribute__((ext_vector_type(4)));

__device__ __forceinline__ unsigned short f2bf(float f) {
  __bf16 h = (__bf16)f;
  return __builtin_bit_cast(unsigned short, h);
}

// async global->LDS, 16B per lane. LDS dest = wave-uniform base + lane*16.
__device__ __forceinline__ void g2l16(const void* g, void* l) {
  __builtin_amdgcn_global_load_lds((__attribute__((address_space(1))) void*)g,
                                   (__attribute__((address_space(3))) void*)l,
                                   16, 0, 0);
}

// ---------------------------------------------------------------- cvt fp32->bf16
__global__ __launch_bounds__(256) void cvt_bf16_kernel(const float* __restrict__ in,
                                                       unsigned short* __restrict__ out) {
  int i = (blockIdx.x * 256 + threadIdx.x) * 8;
  float4 a = *(const float4*)(in + i);
  float4 b = *(const float4*)(in + i + 4);
  union { unsigned short u[8]; uint4 v; } p;
  p.u[0] = f2bf(a.x); p.u[1] = f2bf(a.y); p.u[2] = f2bf(a.z); p.u[3] = f2bf(a.w);
  p.u[4] = f2bf(b.x); p.u[5] = f2bf(b.y); p.u[6] = f2bf(b.z); p.u[7] = f2bf(b.w);
  *(uint4*)(out + i) = p.v;
}

// ------------------------------------------- transpose + cvt: in (R,C) f32 -> out (C,R) bf16
__global__ __launch_bounds__(256) void tcvt_kernel(const float* __restrict__ in,
                                                   unsigned short* __restrict__ out,
                                                   int R, int C) {
  __shared__ float tile[64][65];
  int tx = threadIdx.x & 63;
  int ty = threadIdx.x >> 6;
  int c0 = blockIdx.x * 64;
  int r0 = blockIdx.y * 64;
#pragma unroll
  for (int i = 0; i < 16; ++i) {
    int r = ty + i * 4;
    tile[r][tx] = in[(size_t)(r0 + r) * C + c0 + tx];
  }
  __syncthreads();
#pragma unroll
  for (int i = 0; i < 16; ++i) {
    int rr = ty + i * 4;
    out[(size_t)(c0 + rr) * R + r0 + tx] = f2bf(tile[tx][rr]);
  }
}

// ================================================================= gemm256
// C = A @ Bt^T + bias. A:(M,K) bf16 rm, Bt:(N,K) bf16 rm.
// 256x256 tile, BK=64, 512 threads = 8 waves (2M x 4N), per-wave C = 128x64
// (8 mi x 4 ni fragments of 16x16x32 MFMA). LDS 128 KiB: 2 bufs x (A 256x64 + B 256x64) bf16.
// Chunk XOR-swizzle (slot cp holds chunk cp ^ (row&7)) -> conflict-free ds_read_b128 AND
// linear wave-contiguous global_load_lds staging (rule #21: swizzle on BOTH source & read).
//
// 8-phase schedule, 2 K-tiles (t even in buf0, t+1 in buf1) per iteration.
// Phase q of a tile reads A rows q*32..q*32+32 (per wave) + ALL B-frags at q==0.
// A-half h = per-wave rows [h*64, h*64+64)  -> LDS row sets h0={0-63,128-191}, h1={64-127,192-255}
//   (h0 read in phases q0-1 only, h1 in q2-3 only -> frees early).
// B-half h = rows [h*128, h*128+128)        -> all B read in the tile's FIRST phase only.
// Stage slots (1 half = 2 x global_load_lds/thread):
//   ph1: A-h1(t+1)->buf1   ph2: B-h0(t+2)->buf0   ph3: B-h1(t+2)->buf0   ph4: A-h0(t+2)->buf0
//   ph5: A-h1(t+2)->buf0   ph6: B-h0(t+3)->buf1   ph7: B-h1(t+3)->buf1   ph8: A-h0(t+3)->buf1
// Checkpoints: s_waitcnt vmcnt(6) (3 half-stages in flight) + barrier at ph4 & ph8 only —
// guarantees: ph4 covers stages <= ph1 (tile t+1 complete before ph5 reads);
//             ph8 covers stages <= ph5 (tile t+2 complete before next ph1 reads).
// Clobber-safety: every stage writes a half whose previous data's last reader passed a
// barrier before the stage issues (verified per-slot; e.g. ph4 writes A-h0 while ph4 reads
// A-h1 only). Last iteration: only ph1 stage, vmcnt(0) at ph4.
enum { EPI_F32 = 0, EPI_RELU_BF16 = 1, EPI_QK = 2 };

#define FENCE()   asm volatile("" ::: "memory")
#define BARRIER() do { FENCE(); __builtin_amdgcn_s_barrier(); FENCE(); } while (0)
#define VM6()     asm volatile("s_waitcnt vmcnt(6)" ::: "memory")
#define VM0()     asm volatile("s_waitcnt vmcnt(0)" ::: "memory")
#define NOP_()    do {} while (0)

template <int EPI>
__global__ __launch_bounds__(512, 2) void gemm256(const unsigned short* __restrict__ A,
                                                  const unsigned short* __restrict__ Bt,
                                                  const float* __restrict__ bias,
                                                  void* __restrict__ outp,
                                                  int Mdim, int Ndim, int Kdim) {
  extern __shared__ unsigned short lds[];
  const int tid  = threadIdx.x;
  const int wid  = tid >> 6;
  const int lane = tid & 63;
  const int quad = lane >> 4;
  const int l16  = lane & 15;
  const int wm   = wid >> 2;   // 0..1
  const int wn   = wid & 3;    // 0..3

  // T1: bijective XCD swizzle (nwg % 8 == 0 for all our shapes)
  const int nbx = Ndim >> 8;
  const int nwg = (Mdim >> 8) * nbx;
  const int bid = (int)blockIdx.x;
  const int lin = (bid & 7) * (nwg >> 3) + (bid >> 3);
  const int bx  = lin % nbx;
  const int by  = lin / nbx;
  const int bn0 = bx << 8;
  const int bm0 = by << 8;

  unsigned short* const Ab[2] = { lds,         lds + 32768 };
  unsigned short* const Bb[2] = { lds + 16384, lds + 49152 };

  // staging geometry: thread covers chunk (m_l, slot tid&7) of each 64-row round;
  // source chunk pre-swizzled so LDS stays linear for global_load_lds.
  const int m_l = tid >> 3;
  const int c_l = (tid & 7) ^ (m_l & 7);
  const unsigned short* gA = A  + (size_t)(bm0 + m_l) * (size_t)Kdim + c_l * 8;
  const unsigned short* gB = Bt + (size_t)(bn0 + m_l) * (size_t)Kdim + c_l * 8;
  const int ldsW = wid * 512;  // ushort offset of wave's first chunk within a 64-row round

#define SR_(g, mb, R0, kofs) \
  g2l16((g) + (size_t)(R0) * (size_t)Kdim + (size_t)(kofs), (mb) + (R0) * 64 + ldsW)
#define STG_A(b, h, kofs) do { SR_(gA, Ab[b], (h)*64,  (kofs)); SR_(gA, Ab[b], (h)*64 + 128, (kofs)); } while (0)
#define STG_B(b, h, kofs) do { SR_(gB, Bb[b], (h)*128, (kofs)); SR_(gB, Bb[b], (h)*128 + 64, (kofs)); } while (0)

  // fragment read geometry: row&7 == l16&7 for all fragments -> lane-constant swizzle slots
  const int aro = wm * 128 + l16;
  const int bro = wn * 64  + l16;
  const int cs0 = ((0 + quad) ^ (l16 & 7)) * 8;
  const int cs1 = ((4 + quad) ^ (l16 & 7)) * 8;

  f32x4 zero = {0.f, 0.f, 0.f, 0.f};
  f32x4 acc[8][4];
#pragma unroll
  for (int i = 0; i < 8; ++i)
#pragma unroll
    for (int j = 0; j < 4; ++j) acc[i][j] = zero;
  bf16x8 bfr[4][2];

#define RD_A(bsel, q, af)                                             \
  do {                                                                \
    const unsigned short* Abase = Ab[bsel];                           \
    _Pragma("unroll") for (int d = 0; d < 2; ++d) {                   \
      const int ro = (aro + ((q) * 2 + d) * 16) * 64;                 \
      af[d][0] = *(const bf16x8*)&Abase[ro + cs0];                    \
      af[d][1] = *(const bf16x8*)&Abase[ro + cs1];                    \
    }                                                                 \
  } while (0)

#define RD_B(bsel)                                                    \
  do {                                                                \
    const unsigned short* Bbase = Bb[bsel];                           \
    _Pragma("unroll") for (int n = 0; n < 4; ++n) {                   \
      const int ro = (bro + n * 16) * 64;                             \
      bfr[n][0] = *(const bf16x8*)&Bbase[ro + cs0];                   \
      bfr[n][1] = *(const bf16x8*)&Bbase[ro + cs1];                   \
    }                                                                 \
  } while (0)

#define MFMA16(q, af)                                                                      \
  do {                                                                                     \
    __builtin_amdgcn_s_setprio(1);                                                         \
    _Pragma("unroll") for (int kk = 0; kk < 2; ++kk)                                       \
      _Pragma("unroll") for (int d = 0; d < 2; ++d)                                        \
        _Pragma("unroll") for (int n = 0; n < 4; ++n)                                      \
          acc[(q) * 2 + d][n] = __builtin_amdgcn_mfma_f32_16x16x32_bf16(                   \
              af[d][kk], bfr[n][kk], acc[(q) * 2 + d][n], 0, 0, 0);                        \
    __builtin_amdgcn_s_setprio(0);                                                         \
  } while (0)

#define PHASE(bsel, q, STAGES, VMW)  \
  do {                               \
    bf16x8 af[2][2];                 \
    RD_A(bsel, q, af);               \
    if ((q) == 0) RD_B(bsel);        \
    STAGES;                          \
    BARRIER();                       \
    MFMA16(q, af);                   \
    VMW;                             \
    BARRIER();                       \
  } while (0)

  // prologue: tile0 complete + tile1 {B0,B1,A0}; vmcnt(6) -> tile0 landed
  STG_B(0, 0, 0);  STG_B(0, 1, 0);  STG_A(0, 0, 0);  STG_A(0, 1, 0);
  STG_B(1, 0, 64); STG_B(1, 1, 64); STG_A(1, 0, 64);
  VM6();
  BARRIER();

  const int NI = Kdim >> 7;  // iterations of 2 K-tiles
#pragma unroll 1
  for (int i = 0; i < NI - 1; ++i) {
    const int kb = i << 7;
    PHASE(0, 0, STG_A(1, 1, kb + 64),  NOP_());
    PHASE(0, 1, STG_B(0, 0, kb + 128), NOP_());
    PHASE(0, 2, STG_B(0, 1, kb + 128), NOP_());
    PHASE(0, 3, STG_A(0, 0, kb + 128), VM6());
    PHASE(1, 0, STG_A(0, 1, kb + 128), NOP_());
    PHASE(1, 1, STG_B(1, 0, kb + 192), NOP_());
    PHASE(1, 2, STG_B(1, 1, kb + 192), NOP_());
    PHASE(1, 3, STG_A(1, 0, kb + 192), VM6());
  }
  {  // last iteration: only ph1 stage remains; drain at ph4
    const int kb = (NI - 1) << 7;
    PHASE(0, 0, STG_A(1, 1, kb + 64), NOP_());
    PHASE(0, 1, NOP_(), NOP_());
    PHASE(0, 2, NOP_(), NOP_());
    PHASE(0, 3, NOP_(), VM0());
    PHASE(1, 0, NOP_(), NOP_());
    PHASE(1, 1, NOP_(), NOP_());
    PHASE(1, 2, NOP_(), NOP_());
    PHASE(1, 3, NOP_(), NOP_());
  }

  // epilogue
  float bv[4];
#pragma unroll
  for (int ni = 0; ni < 4; ++ni) bv[ni] = bias[bn0 + wn * 64 + ni * 16 + l16];

#pragma unroll
  for (int mi = 0; mi < 8; ++mi) {
#pragma unroll
    for (int ni = 0; ni < 4; ++ni) {
      const int n = bn0 + wn * 64 + ni * 16 + l16;
#pragma unroll
      for (int r = 0; r < 4; ++r) {
        const int m = bm0 + wm * 128 + mi * 16 + quad * 4 + r;
        float v = acc[mi][ni][r] + bv[ni];
        if (EPI == EPI_F32) {
          ((float*)outp)[(size_t)m * Ndim + n] = v;
        } else if (EPI == EPI_RELU_BF16) {
          ((unsigned short*)outp)[(size_t)m * Ndim + n] = f2bf(fmaxf(v, 0.f));
        } else {  // EPI_QK: scatter (m=b*T+t, n=h*DK+dk) -> (b,h,t,dk)
          int bb = m >> 7, tt = m & 127, hh = n >> 7, dk = n & 127;
          ((unsigned short*)outp)[((size_t)(bb * H_ + hh) * T_ + tt) * DK_ + dk] = f2bf(v);
        }
      }
    }
  }
#undef SR_
#undef STG_A
#undef STG_B
#undef RD_A
#undef RD_B
#undef MFMA16
#undef PHASE
}

// --------------------------- attention: S = Q K^T / sqrt(DK), softmax rows, write (b,t,h,t2)
__global__ __launch_bounds__(256) void attn_kernel(const unsigned short* __restrict__ qb,
                                                   const unsigned short* __restrict__ kb,
                                                   unsigned short* __restrict__ attn) {
  __shared__ alignas(16) unsigned short Qs[128 * 128];
  __shared__ alignas(16) unsigned short Ks[128 * 128];
  const int tid  = threadIdx.x;
  const int wid  = tid >> 6;
  const int lane = tid & 63;
  const int quad = lane >> 4;
  const int l16  = lane & 15;
  const int bx   = blockIdx.x;
  const int b    = bx >> 5;
  const int h    = bx & 31;
  const unsigned short* gq = qb + (size_t)bx * (T_ * DK_);
  const unsigned short* gk = kb + (size_t)bx * (T_ * DK_);

#pragma unroll
  for (int r = 0; r < 8; ++r) {
    int s = r * 256 + tid;
    int m = s >> 4, cp = s & 15;
    int c = cp ^ (m & 15);
    unsigned lb = (unsigned)(r * 256 + wid * 64) * 8;
    g2l16(gq + m * 128 + c * 8, &Qs[lb]);
    g2l16(gk + m * 128 + c * 8, &Ks[lb]);
  }
  __syncthreads();

  f32x4 zero = {0.f, 0.f, 0.f, 0.f};
  f32x4 acc[2][8];
#pragma unroll
  for (int i = 0; i < 2; ++i)
#pragma unroll
    for (int j = 0; j < 8; ++j) acc[i][j] = zero;

#pragma unroll
  for (int st = 0; st < 4; ++st) {
    bf16x8 a[2], bfr[8];
#pragma unroll
    for (int mi = 0; mi < 2; ++mi) {
      int row = wid * 32 + mi * 16 + l16;
      int cp  = (st * 4 + quad) ^ (row & 15);
      a[mi]   = *(const bf16x8*)&Qs[row * 128 + cp * 8];
    }
#pragma unroll
    for (int ni = 0; ni < 8; ++ni) {
      int row = ni * 16 + l16;
      int cp  = (st * 4 + quad) ^ (row & 15);
      bfr[ni] = *(const bf16x8*)&Ks[row * 128 + cp * 8];
    }
#pragma unroll
    for (int mi = 0; mi < 2; ++mi)
#pragma unroll
      for (int ni = 0; ni < 8; ++ni)
        acc[mi][ni] = __builtin_amdgcn_mfma_f32_16x16x32_bf16(a[mi], bfr[ni],
                                                              acc[mi][ni], 0, 0, 0);
  }

  const float scale = 0.08838834764831845f;  // 1/sqrt(128)
#pragma unroll
  for (int mi = 0; mi < 2; ++mi) {
#pragma unroll
    for (int r = 0; r < 4; ++r) {
      float v[8];
      float mx = -1e30f;
#pragma unroll
      for (int ni = 0; ni < 8; ++ni) {
        v[ni] = acc[mi][ni][r] * scale;
        mx    = fmaxf(mx, v[ni]);
      }
      mx = fmaxf(mx, __shfl_xor(mx, 1, 64));
      mx = fmaxf(mx, __shfl_xor(mx, 2, 64));
      mx = fmaxf(mx, __shfl_xor(mx, 4, 64));
      mx = fmaxf(mx, __shfl_xor(mx, 8, 64));
      float sum = 0.f;
#pragma unroll
      for (int ni = 0; ni < 8; ++ni) {
        v[ni] = __expf(v[ni] - mx);
        sum += v[ni];
      }
      sum += __shfl_xor(sum, 1, 64);
      sum += __shfl_xor(sum, 2, 64);
      sum += __shfl_xor(sum, 4, 64);
      sum += __shfl_xor(sum, 8, 64);
      float inv = 1.0f / sum;
      int rowg  = wid * 32 + mi * 16 + quad * 4 + r;
      size_t base = ((size_t)b * T_ + rowg) * E_ + h * T_;
#pragma unroll
      for (int ni = 0; ni < 8; ++ni)
        attn[base + ni * 16 + l16] = f2bf(v[ni] * inv);
    }
  }
}

// --------------------------------- LN(a + bsrc)*g + beta ; optional bf16 copy of output
__global__ __launch_bounds__(256) void ln_kernel(const float* __restrict__ a,
                                                 const float* __restrict__ bsrc,
                                                 const float* __restrict__ g,
                                                 const float* __restrict__ bet,
                                                 float* __restrict__ out32,
                                                 unsigned short* __restrict__ out16) {
  const int row = blockIdx.x;
  const int tid = threadIdx.x;
  const float* pa = a + (size_t)row * E_;
  const float* pb = bsrc + (size_t)row * E_;
  float4 xv[4];
  float s = 0.f, ss = 0.f;
#pragma unroll
  for (int i = 0; i < 4; ++i) {
    int c = tid * 4 + i * 1024;
    float4 va = *(const float4*)(pa + c);
    float4 vb = *(const float4*)(pb + c);
    float4 x;
    x.x = va.x + vb.x; x.y = va.y + vb.y; x.z = va.z + vb.z; x.w = va.w + vb.w;
    xv[i] = x;
    s  += x.x + x.y + x.z + x.w;
    ss += x.x * x.x + x.y * x.y + x.z * x.z + x.w * x.w;
  }
#pragma unroll
  for (int m = 32; m >= 1; m >>= 1) {
    s  += __shfl_xor(s, m, 64);
    ss += __shfl_xor(ss, m, 64);
  }
  __shared__ float red[8];
  int wid = tid >> 6, lane = tid & 63;
  if (lane == 0) { red[wid] = s; red[4 + wid] = ss; }
  __syncthreads();
  s  = red[0] + red[1] + red[2] + red[3];
  ss = red[4] + red[5] + red[6] + red[7];
  float mean = s * (1.0f / 4096.0f);
  float var  = ss * (1.0f / 4096.0f) - mean * mean;
  float rstd = rsqrtf(var + 1e-5f);
#pragma unroll
  for (int i = 0; i < 4; ++i) {
    int c = tid * 4 + i * 1024;
    float4 gv = *(const float4*)(g + c);
    float4 bv = *(const float4*)(bet + c);
    float4 y;
    y.x = (xv[i].x - mean) * rstd * gv.x + bv.x;
    y.y = (xv[i].y - mean) * rstd * gv.y + bv.y;
    y.z = (xv[i].z - mean) * rstd * gv.z + bv.z;
    y.w = (xv[i].w - mean) * rstd * gv.w + bv.w;
    *(float4*)(out32 + (size_t)row * E_ + c) = y;
    if (out16) {
      ushort4 u;
      u.x = f2bf(y.x); u.y = f2bf(y.y); u.z = f2bf(y.z); u.w = f2bf(y.w);
      *(ushort4*)(out16 + (size_t)row * E_ + c) = u;
    }
  }
}

// ---------------------------------------------------------------- launch
extern "C" void kernel_launch(void* const* d_in, const int* in_sizes, int n_in,
                              void* d_out, int out_size, void* d_ws, size_t ws_size,
                              hipStream_t stream) {
  const float* x     = (const float*)d_in[0];
  const float* wq    = (const float*)d_in[1];
  const float* bq    = (const float*)d_in[2];
  const float* wk    = (const float*)d_in[3];
  const float* bk    = (const float*)d_in[4];
  // d_in[5]=wv, d_in[6]=bv : unused by the reference
  const float* wo    = (const float*)d_in[7];
  const float* bo    = (const float*)d_in[8];
  const float* w1    = (const float*)d_in[9];
  const float* b1    = (const float*)d_in[10];
  const float* w2    = (const float*)d_in[11];
  const float* b2    = (const float*)d_in[12];
  const float* g1    = (const float*)d_in[13];
  const float* beta1 = (const float*)d_in[14];
  const float* g2    = (const float*)d_in[15];
  const float* beta2 = (const float*)d_in[16];

  // enable 128 KiB dynamic LDS for the gemm instantiations (host-side, capture-safe)
  static bool s_attr = false;
  if (!s_attr) {
    hipFuncSetAttribute(reinterpret_cast<const void*>(&gemm256<EPI_F32>),
                        hipFuncAttributeMaxDynamicSharedMemorySize, 131072);
    hipFuncSetAttribute(reinterpret_cast<const void*>(&gemm256<EPI_RELU_BF16>),
                        hipFuncAttributeMaxDynamicSharedMemorySize, 131072);
    hipFuncSetAttribute(reinterpret_cast<const void*>(&gemm256<EPI_QK>),
                        hipFuncAttributeMaxDynamicSharedMemorySize, 131072);
    s_attr = true;
  }

  // workspace layout (448 MiB total)
  char* ws = (char*)d_ws;
  const size_t SZ_ME_BF = (size_t)M_ * E_ * 2;   //  33,554,432
  const size_t SZ_EF_BF = (size_t)E_ * F_ * 2;   // 134,217,728
  const size_t SZ_ME_F  = (size_t)M_ * E_ * 4;   //  67,108,864
  unsigned short* xb   = (unsigned short*)ws;                   // R0
  unsigned short* wbuf = (unsigned short*)(ws + SZ_ME_BF);      // R1 (reused 5x)
  char* r2 = ws + SZ_ME_BF + SZ_EF_BF;                          // R2: qb+kb / o / f
  char* r3 = r2 + SZ_ME_F;                                      // R3: attn / x1b
  char* r4 = r3 + SZ_ME_BF;                                     // R4: x1 fp32
  char* r5 = r4 + SZ_ME_F;                                      // R5: h bf16

  unsigned short* qb   = (unsigned short*)r2;
  unsigned short* kb   = (unsigned short*)(r2 + SZ_ME_BF);
  unsigned short* attn = (unsigned short*)r3;
  float*          o    = (float*)r2;
  float*          x1   = (float*)r4;
  unsigned short* x1b  = (unsigned short*)r3;
  unsigned short* hbuf = (unsigned short*)r5;
  float*          fbuf = (float*)r2;

  const int GRID_EE = (M_ / 256) * (E_ / 256);   // 256
  const int GRID_EF = (M_ / 256) * (F_ / 256);   // 1024

  // x -> bf16
  cvt_bf16_kernel<<<(M_ * E_) / (256 * 8), 256, 0, stream>>>(x, xb);

  // q = x@wq + bq  -> (B,H,T,DK) bf16
  tcvt_kernel<<<dim3(E_ / 64, E_ / 64), 256, 0, stream>>>(wq, wbuf, E_, E_);
  gemm256<EPI_QK><<<GRID_EE, 512, 131072, stream>>>(xb, wbuf, bq, qb, M_, E_, E_);

  // k = x@wk + bk
  tcvt_kernel<<<dim3(E_ / 64, E_ / 64), 256, 0, stream>>>(wk, wbuf, E_, E_);
  gemm256<EPI_QK><<<GRID_EE, 512, 131072, stream>>>(xb, wbuf, bk, kb, M_, E_, E_);

  // attn = softmax(qk^T/sqrt(dk)) in (B,T,H*T) layout
  attn_kernel<<<B_ * H_, 256, 0, stream>>>(qb, kb, attn);

  // o = attn@wo + bo (fp32)
  tcvt_kernel<<<dim3(E_ / 64, E_ / 64), 256, 0, stream>>>(wo, wbuf, E_, E_);
  gemm256<EPI_F32><<<GRID_EE, 512, 131072, stream>>>(attn, wbuf, bo, o, M_, E_, E_);

  // x1 = LN(x + o)
  ln_kernel<<<M_, 256, 0, stream>>>(x, o, g1, beta1, x1, x1b);

  // h = relu(x1@w1 + b1) bf16
  tcvt_kernel<<<dim3(F_ / 64, E_ / 64), 256, 0, stream>>>(w1, wbuf, E_, F_);
  gemm256<EPI_RELU_BF16><<<GRID_EF, 512, 131072, stream>>>(x1b, wbuf, b1, hbuf, M_, F_, E_);

  // f = h@w2 + b2 (fp32)
  tcvt_kernel<<<dim3(E_ / 64, F_ / 64), 256, 0, stream>>>(w2, wbuf, F_, E_);
  gemm256<EPI_F32><<<GRID_EE, 512, 131072, stream>>>(hbuf, wbuf, b2, fbuf, M_, E_, F_);

  // out = LN(x1 + f)
  ln_kernel<<<M_, 256, 0, stream>>>(x1, fbuf, g2, beta2, (float*)d_out, nullptr);
}